// Round 2
// baseline (2433.730 us; speedup 1.0000x reference)
//
#include <hip/hip_runtime.h>
#include <math.h>

#define N_NODES 150000
#define D 64
#define NEDGE 4800000
#define NUM_LAYERS 3

#define SCAN_BLOCK 256
#define SCAN_CHUNK 2048  // 256 threads * 8 elems
#define NSCAN_BLOCKS ((N_NODES + SCAN_CHUNK - 1) / SCAN_CHUNK)  // 74

// buckets of 256 destination nodes each
#define BSHIFT 8
#define NBUCKET ((N_NODES + 255) >> 8)  // 586

// ---- degree count (int atomics) ----
__global__ void deg_kernel(const int* __restrict__ col, int* __restrict__ deg) {
    int i = blockIdx.x * blockDim.x + threadIdx.x;
    int stride = gridDim.x * blockDim.x;
    for (int e = i; e < NEDGE; e += stride)
        atomicAdd(&deg[col[e]], 1);
}

// ---- deg_inv_sqrt ----
__global__ void dis_kernel(const int* __restrict__ deg, float* __restrict__ dis) {
    int i = blockIdx.x * blockDim.x + threadIdx.x;
    if (i < N_NODES) {
        int d = deg[i];
        dis[i] = (d > 0) ? (1.0f / sqrtf((float)d)) : 0.0f;
    }
}

// ---- exclusive scan of deg -> off ----
__global__ void scan1(const int* __restrict__ deg, int* __restrict__ off,
                      int* __restrict__ blk_sums) {
    __shared__ int tsum[SCAN_BLOCK];
    int b = blockIdx.x, t = threadIdx.x;
    int base = b * SCAN_CHUNK + t * 8;
    int v[8];
    int s = 0;
#pragma unroll
    for (int k = 0; k < 8; k++) {
        int idx = base + k;
        v[k] = (idx < N_NODES) ? deg[idx] : 0;
        s += v[k];
    }
    tsum[t] = s;
    __syncthreads();
    for (int ofs = 1; ofs < SCAN_BLOCK; ofs <<= 1) {
        int xv = (t >= ofs) ? tsum[t - ofs] : 0;
        __syncthreads();
        tsum[t] += xv;
        __syncthreads();
    }
    int excl = (t > 0) ? tsum[t - 1] : 0;
    if (t == SCAN_BLOCK - 1) blk_sums[b] = tsum[t];
    int run = excl;
#pragma unroll
    for (int k = 0; k < 8; k++) {
        int idx = base + k;
        if (idx < N_NODES) off[idx] = run;
        run += v[k];
    }
}

__global__ void scan2(const int* __restrict__ blk_sums, int* __restrict__ blk_off) {
    if (threadIdx.x == 0) {
        int run = 0;
        for (int b = 0; b < NSCAN_BLOCKS; b++) {
            blk_off[b] = run;
            run += blk_sums[b];
        }
    }
}

__global__ void scan3(int* __restrict__ off, const int* __restrict__ blk_off,
                      int* __restrict__ cursor) {
    int i = blockIdx.x * blockDim.x + threadIdx.x;
    if (i < N_NODES) {
        int v = off[i] + blk_off[i / SCAN_CHUNK];
        off[i] = v;
        cursor[i] = v;
    }
    if (i == 0) off[N_NODES] = NEDGE;
}

// ---- init bucket cursors from node offsets (bucket start = off[b*256]) ----
__global__ void binit(const int* __restrict__ off, int* __restrict__ bcur) {
    int b = blockIdx.x * blockDim.x + threadIdx.x;
    if (b < NBUCKET) bcur[b] = off[b << BSHIFT];
}

// ---- pass 1: bin edges by dst bucket; packed record: row(18b) | col_low(8b)<<18 ----
__global__ void binpass(const int* __restrict__ row, const int* __restrict__ col,
                        int* __restrict__ bcur, unsigned* __restrict__ pk) {
    int i = blockIdx.x * blockDim.x + threadIdx.x;
    int stride = gridDim.x * blockDim.x;
    for (int e = i; e < NEDGE; e += stride) {
        int c = col[e];
        int r = row[e];
        int b = c >> BSHIFT;
        int pos = atomicAdd(&bcur[b], 1);
        pk[pos] = (unsigned)r | ((unsigned)(c & 255) << 18);
    }
}

// ---- pass 2: within-bucket counting-sort scatter; write packed {row, dis[row]} ----
__global__ void sortpass(const unsigned* __restrict__ pk, const int* __restrict__ off,
                         int* __restrict__ cursor, const float* __restrict__ dis,
                         int2* __restrict__ ew) {
    int b = blockIdx.x;
    int s = off[b << BSHIFT];
    int hi = (b + 1) << BSHIFT;
    if (hi > N_NODES) hi = N_NODES;
    int e = off[hi];
    for (int i = s + threadIdx.x; i < e; i += blockDim.x) {
        unsigned v = pk[i];
        int r = (int)(v & 0x3FFFFu);
        int c = (b << BSHIFT) | (int)(v >> 18);
        int pos = atomicAdd(&cursor[c], 1);
        ew[pos] = make_int2(r, __float_as_int(dis[r]));
    }
}

// ---- one propagation layer: wave64 per dest node, lane per feature dim ----
template <bool WRITE_H, bool ACCUM_OUT>
__global__ void layer_kernel(const float* __restrict__ h, const int* __restrict__ off,
                             const int2* __restrict__ ew, const float* __restrict__ dis,
                             float* __restrict__ hout, float* __restrict__ out,
                             float alpha) {
    int wid = (blockIdx.x * blockDim.x + threadIdx.x) >> 6;
    int lane = threadIdx.x & 63;
    if (wid >= N_NODES) return;
    int s = off[wid];
    int e = off[wid + 1];
    float acc = 0.0f;
    int i = s;
    for (; i + 1 < e; i += 2) {
        int2 p0 = ew[i];
        int2 p1 = ew[i + 1];
        float a0 = h[(size_t)p0.x * D + lane];
        float a1 = h[(size_t)p1.x * D + lane];
        acc += __int_as_float(p0.y) * a0;
        acc += __int_as_float(p1.y) * a1;
    }
    if (i < e) {
        int2 p = ew[i];
        acc += __int_as_float(p.y) * h[(size_t)p.x * D + lane];
    }
    float val = dis[wid] * acc;
    size_t o = (size_t)wid * D + lane;
    if (WRITE_H) hout[o] = val;
    if (ACCUM_OUT)
        out[o] = out[o] + alpha * val;
    else
        out[o] = alpha * val;
}

extern "C" void kernel_launch(void* const* d_in, const int* in_sizes, int n_in,
                              void* d_out, int out_size, void* d_ws, size_t ws_size,
                              hipStream_t stream) {
    const float* x = (const float*)d_in[0];
    const int* edges = (const int*)d_in[1];
    const int* row = edges;          // edge_index[0]
    const int* col = edges + NEDGE;  // edge_index[1]
    float* out = (float*)d_out;

    char* ws = (char*)d_ws;
    size_t p = 0;
    auto alloc = [&](size_t bytes) {
        void* r = ws + p;
        p += (bytes + 255) & ~(size_t)255;
        return r;
    };
    int* deg = (int*)alloc((size_t)N_NODES * 4);
    float* dis = (float*)alloc((size_t)N_NODES * 4);
    int* off = (int*)alloc((size_t)(N_NODES + 1) * 4);
    int* cursor = (int*)alloc((size_t)N_NODES * 4);
    int* bcur = (int*)alloc((size_t)NBUCKET * 4);
    int* blk_sums = (int*)alloc((size_t)NSCAN_BLOCKS * 4);
    int* blk_off = (int*)alloc((size_t)NSCAN_BLOCKS * 4);
    int2* ew = (int2*)alloc((size_t)NEDGE * 8);
    // pk is dead after sortpass; hA written after -> alias the same region
    char* region = (char*)alloc((size_t)N_NODES * D * 4);  // 38.4 MB >= pk's 19.2 MB
    unsigned* pk = (unsigned*)region;
    float* hA = (float*)region;
    float* hB = (float*)alloc((size_t)N_NODES * D * 4);

    hipMemsetAsync(deg, 0, (size_t)N_NODES * 4, stream);
    deg_kernel<<<2048, 256, 0, stream>>>(col, deg);
    int nblk_n = (N_NODES + 255) / 256;
    dis_kernel<<<nblk_n, 256, 0, stream>>>(deg, dis);
    scan1<<<NSCAN_BLOCKS, SCAN_BLOCK, 0, stream>>>(deg, off, blk_sums);
    scan2<<<1, 64, 0, stream>>>(blk_sums, blk_off);
    scan3<<<nblk_n, 256, 0, stream>>>(off, blk_off, cursor);
    binit<<<(NBUCKET + 255) / 256, 256, 0, stream>>>(off, bcur);
    binpass<<<2048, 256, 0, stream>>>(row, col, bcur, pk);
    sortpass<<<NBUCKET, 256, 0, stream>>>(pk, off, cursor, dis, ew);

    const float alpha = 1.0f / (1.0f + NUM_LAYERS);
    int grid = (N_NODES * D + 255) / 256;  // one wave64 per node
    layer_kernel<true, false><<<grid, 256, 0, stream>>>(x, off, ew, dis, hA, out, alpha);
    layer_kernel<true, true><<<grid, 256, 0, stream>>>(hA, off, ew, dis, hB, out, alpha);
    layer_kernel<false, true><<<grid, 256, 0, stream>>>(hB, off, ew, dis, nullptr, out, alpha);
}

// Round 3
// 1028.319 us; speedup vs baseline: 2.3667x; 2.3667x over previous
//
#include <hip/hip_runtime.h>
#include <math.h>

#define N_NODES 150000
#define D 64
#define NEDGE 4800000
#define NUM_LAYERS 3

#define SCAN_BLOCK 256
#define SCAN_CHUNK 2048  // 256 threads * 8 elems
#define NSCAN_BLOCKS ((N_NODES + SCAN_CHUNK - 1) / SCAN_CHUNK)  // 74

// ---- degree count (int atomics over 150k counters: low contention) ----
__global__ void deg_kernel(const int* __restrict__ col, int* __restrict__ deg) {
    int i = blockIdx.x * blockDim.x + threadIdx.x;
    int stride = gridDim.x * blockDim.x;
    for (int e = i; e < NEDGE; e += stride)
        atomicAdd(&deg[col[e]], 1);
}

// ---- exclusive scan of deg -> off ----
__global__ void scan1(const int* __restrict__ deg, int* __restrict__ off,
                      int* __restrict__ blk_sums) {
    __shared__ int tsum[SCAN_BLOCK];
    int b = blockIdx.x, t = threadIdx.x;
    int base = b * SCAN_CHUNK + t * 8;
    int v[8];
    int s = 0;
#pragma unroll
    for (int k = 0; k < 8; k++) {
        int idx = base + k;
        v[k] = (idx < N_NODES) ? deg[idx] : 0;
        s += v[k];
    }
    tsum[t] = s;
    __syncthreads();
    for (int ofs = 1; ofs < SCAN_BLOCK; ofs <<= 1) {
        int xv = (t >= ofs) ? tsum[t - ofs] : 0;
        __syncthreads();
        tsum[t] += xv;
        __syncthreads();
    }
    int excl = (t > 0) ? tsum[t - 1] : 0;
    if (t == SCAN_BLOCK - 1) blk_sums[b] = tsum[t];
    int run = excl;
#pragma unroll
    for (int k = 0; k < 8; k++) {
        int idx = base + k;
        if (idx < N_NODES) off[idx] = run;
        run += v[k];
    }
}

__global__ void scan2(const int* __restrict__ blk_sums, int* __restrict__ blk_off) {
    if (threadIdx.x == 0) {
        int run = 0;
        for (int b = 0; b < NSCAN_BLOCKS; b++) {
            blk_off[b] = run;
            run += blk_sums[b];
        }
    }
}

// finalize offsets + init cursor + compute deg_inv_sqrt (fused)
__global__ void scan3(int* __restrict__ off, const int* __restrict__ blk_off,
                      int* __restrict__ cursor, const int* __restrict__ deg,
                      float* __restrict__ dis) {
    int i = blockIdx.x * blockDim.x + threadIdx.x;
    if (i < N_NODES) {
        int v = off[i] + blk_off[i / SCAN_CHUNK];
        off[i] = v;
        cursor[i] = v;
        int d = deg[i];
        dis[i] = (d > 0) ? (1.0f / sqrtf((float)d)) : 0.0f;
    }
    if (i == 0) off[N_NODES] = NEDGE;
}

// ---- single-pass scatter into CSR order, writing packed {row, dis[row]} ----
__global__ void scatter_ew(const int* __restrict__ row, const int* __restrict__ col,
                           int* __restrict__ cursor, const float* __restrict__ dis,
                           int2* __restrict__ ew) {
    int i = blockIdx.x * blockDim.x + threadIdx.x;
    int stride = gridDim.x * blockDim.x;
    for (int e = i; e < NEDGE; e += stride) {
        int c = col[e];
        int r = row[e];
        int pos = atomicAdd(&cursor[c], 1);
        ew[pos] = make_int2(r, __float_as_int(dis[r]));
    }
}

// ---- propagation layer: wave64 per dest node, 4 edge-groups x 16 lanes x float4 ----
template <bool FINAL>
__global__ void layer4(const float4* __restrict__ h4, const int* __restrict__ off,
                       const int2* __restrict__ ew, const float* __restrict__ dis,
                       float4* __restrict__ hout4, const float4* __restrict__ hA4,
                       const float4* __restrict__ hB4, float4* __restrict__ out4,
                       float alpha) {
    int wid = (blockIdx.x * blockDim.x + threadIdx.x) >> 6;
    if (wid >= N_NODES) return;
    int lane = threadIdx.x & 63;
    int g = lane >> 4;    // edge group 0..3
    int sub = lane & 15;  // float4 slot within D=64
    int s = off[wid], e = off[wid + 1];
    float4 acc = make_float4(0.f, 0.f, 0.f, 0.f);
    int i = s + g;
    for (; i + 4 < e; i += 8) {  // 2 edges per group in flight
        int2 p0 = ew[i];
        int2 p1 = ew[i + 4];
        float4 v0 = h4[(size_t)p0.x * 16 + sub];
        float4 v1 = h4[(size_t)p1.x * 16 + sub];
        float w0 = __int_as_float(p0.y);
        float w1 = __int_as_float(p1.y);
        acc.x += w0 * v0.x; acc.y += w0 * v0.y; acc.z += w0 * v0.z; acc.w += w0 * v0.w;
        acc.x += w1 * v1.x; acc.y += w1 * v1.y; acc.z += w1 * v1.z; acc.w += w1 * v1.w;
    }
    if (i < e) {
        int2 p = ew[i];
        float4 v = h4[(size_t)p.x * 16 + sub];
        float w = __int_as_float(p.y);
        acc.x += w * v.x; acc.y += w * v.y; acc.z += w * v.z; acc.w += w * v.w;
    }
    // reduce the 4 edge groups (lanes l, l+16, l+32, l+48)
#pragma unroll
    for (int m = 16; m <= 32; m <<= 1) {
        acc.x += __shfl_xor(acc.x, m, 64);
        acc.y += __shfl_xor(acc.y, m, 64);
        acc.z += __shfl_xor(acc.z, m, 64);
        acc.w += __shfl_xor(acc.w, m, 64);
    }
    if (g == 0) {
        float w = dis[wid];
        size_t o = (size_t)wid * 16 + sub;
        if (FINAL) {
            float4 a = hA4[o], b = hB4[o];
            out4[o] = make_float4(alpha * (a.x + b.x + w * acc.x),
                                  alpha * (a.y + b.y + w * acc.y),
                                  alpha * (a.z + b.z + w * acc.z),
                                  alpha * (a.w + b.w + w * acc.w));
        } else {
            hout4[o] = make_float4(w * acc.x, w * acc.y, w * acc.z, w * acc.w);
        }
    }
}

extern "C" void kernel_launch(void* const* d_in, const int* in_sizes, int n_in,
                              void* d_out, int out_size, void* d_ws, size_t ws_size,
                              hipStream_t stream) {
    const float* x = (const float*)d_in[0];
    const int* edges = (const int*)d_in[1];
    const int* row = edges;          // edge_index[0]
    const int* col = edges + NEDGE;  // edge_index[1]
    float4* out4 = (float4*)d_out;

    char* ws = (char*)d_ws;
    size_t p = 0;
    auto alloc = [&](size_t bytes) {
        void* r = ws + p;
        p += (bytes + 255) & ~(size_t)255;
        return r;
    };
    int* deg = (int*)alloc((size_t)N_NODES * 4);
    float* dis = (float*)alloc((size_t)N_NODES * 4);
    int* off = (int*)alloc((size_t)(N_NODES + 1) * 4);
    int* cursor = (int*)alloc((size_t)N_NODES * 4);
    int* blk_sums = (int*)alloc((size_t)NSCAN_BLOCKS * 4);
    int* blk_off = (int*)alloc((size_t)NSCAN_BLOCKS * 4);
    int2* ew = (int2*)alloc((size_t)NEDGE * 8);
    float* hA = (float*)alloc((size_t)N_NODES * D * 4);
    float* hB = (float*)alloc((size_t)N_NODES * D * 4);

    hipMemsetAsync(deg, 0, (size_t)N_NODES * 4, stream);
    deg_kernel<<<2048, 256, 0, stream>>>(col, deg);
    int nblk_n = (N_NODES + 255) / 256;
    scan1<<<NSCAN_BLOCKS, SCAN_BLOCK, 0, stream>>>(deg, off, blk_sums);
    scan2<<<1, 64, 0, stream>>>(blk_sums, blk_off);
    scan3<<<nblk_n, 256, 0, stream>>>(off, blk_off, cursor, deg, dis);
    scatter_ew<<<4096, 256, 0, stream>>>(row, col, cursor, dis, ew);

    const float alpha = 1.0f / (1.0f + NUM_LAYERS);
    int grid = (N_NODES * 64 + 255) / 256;  // one wave64 per node
    layer4<false><<<grid, 256, 0, stream>>>((const float4*)x, off, ew, dis,
                                            (float4*)hA, nullptr, nullptr, nullptr, alpha);
    layer4<false><<<grid, 256, 0, stream>>>((const float4*)hA, off, ew, dis,
                                            (float4*)hB, nullptr, nullptr, nullptr, alpha);
    layer4<true><<<grid, 256, 0, stream>>>((const float4*)hB, off, ew, dis,
                                           nullptr, (const float4*)hA, (const float4*)hB,
                                           out4, alpha);
}

// Round 4
// 635.514 us; speedup vs baseline: 3.8295x; 1.6181x over previous
//
#include <hip/hip_runtime.h>
#include <math.h>

#define N_NODES 150000
#define D 64
#define NEDGE 4800000
#define NUM_LAYERS 3

#define BSHIFT 8
#define NBUCKET ((N_NODES + 255) >> 8)  // 586
#define NBPAD 768                        // 3*256, padded scan width
#define BINTILE 8192
#define NBIN_BLOCKS ((NEDGE + BINTILE - 1) / BINTILE)  // 586

// ---- pass 0: per-bucket edge counts (LDS hist, 1 global atomic/bucket/block) ----
__global__ void hist_bucket(const int4* __restrict__ col4, int* __restrict__ bcount) {
    __shared__ int h[NBUCKET];
    for (int i = threadIdx.x; i < NBUCKET; i += blockDim.x) h[i] = 0;
    __syncthreads();
    int i = blockIdx.x * blockDim.x + threadIdx.x;
    int stride = gridDim.x * blockDim.x;
    for (int e = i; e < NEDGE / 4; e += stride) {
        int4 c = col4[e];
        atomicAdd(&h[c.x >> BSHIFT], 1);
        atomicAdd(&h[c.y >> BSHIFT], 1);
        atomicAdd(&h[c.z >> BSHIFT], 1);
        atomicAdd(&h[c.w >> BSHIFT], 1);
    }
    __syncthreads();
    for (int b = threadIdx.x; b < NBUCKET; b += blockDim.x)
        if (h[b]) atomicAdd(&bcount[b], h[b]);
}

// ---- pass 1: scan bucket counts -> bases; init padded cursors ----
__global__ void scan_buckets(const int* __restrict__ bcount, int* __restrict__ bbase,
                             int* __restrict__ bcur16, int* __restrict__ off) {
    __shared__ int tsum[256];
    int t = threadIdx.x;
    int loc[3];
    int s = 0;
#pragma unroll
    for (int k = 0; k < 3; k++) {
        int idx = t * 3 + k;
        int x = (idx < NBUCKET) ? bcount[idx] : 0;
        loc[k] = x;
        s += x;
    }
    tsum[t] = s;
    __syncthreads();
    for (int ofs = 1; ofs < 256; ofs <<= 1) {
        int xv = (t >= ofs) ? tsum[t - ofs] : 0;
        __syncthreads();
        tsum[t] += xv;
        __syncthreads();
    }
    int run = (t > 0) ? tsum[t - 1] : 0;
#pragma unroll
    for (int k = 0; k < 3; k++) {
        int idx = t * 3 + k;
        if (idx < NBUCKET) bbase[idx] = run;
        bcur16[idx * 16] = run;  // harmless for idx >= NBUCKET (== NEDGE)
        run += loc[k];
    }
    if (t == 255) {
        bbase[NBUCKET] = NEDGE;
        off[N_NODES] = NEDGE;
    }
}

// ---- pass 2: bucket-sort edges via LDS staging; dense write-out of 4B records ----
__global__ void __launch_bounds__(256) binpass2(const int* __restrict__ row,
                                                const int* __restrict__ col,
                                                int* __restrict__ bcur16,
                                                unsigned* __restrict__ bin) {
    __shared__ int hist[NBPAD];
    __shared__ int lscan[NBPAD];
    __shared__ int lcur[NBPAD];
    __shared__ int gbase[NBPAD];
    __shared__ unsigned srec[BINTILE];
    __shared__ unsigned short sbid[BINTILE];
    __shared__ int tsum[256];
    int t = threadIdx.x;
    int base = blockIdx.x * BINTILE;
    int n = NEDGE - base;
    if (n > BINTILE) n = BINTILE;
    for (int i = t; i < NBPAD; i += 256) hist[i] = 0;
    __syncthreads();
    // histogram this tile's cols
    for (int i = t; i < n; i += 256)
        atomicAdd(&hist[col[base + i] >> BSHIFT], 1);
    __syncthreads();
    // exclusive scan over NBPAD (3 consecutive slots/thread)
    int b0 = t * 3;
    int l0 = hist[b0], l1 = hist[b0 + 1], l2 = hist[b0 + 2];
    tsum[t] = l0 + l1 + l2;
    __syncthreads();
    for (int ofs = 1; ofs < 256; ofs <<= 1) {
        int xv = (t >= ofs) ? tsum[t - ofs] : 0;
        __syncthreads();
        tsum[t] += xv;
        __syncthreads();
    }
    int run = (t > 0) ? tsum[t - 1] : 0;
    lscan[b0] = run; lcur[b0] = run;
    lscan[b0 + 1] = run + l0; lcur[b0 + 1] = run + l0;
    lscan[b0 + 2] = run + l0 + l1; lcur[b0 + 2] = run + l0 + l1;
    // reserve global range per bucket (one atomic per non-empty bucket per tile)
    gbase[b0]     = l0 ? atomicAdd(&bcur16[b0 * 16], l0) : 0;
    gbase[b0 + 1] = l1 ? atomicAdd(&bcur16[(b0 + 1) * 16], l1) : 0;
    gbase[b0 + 2] = l2 ? atomicAdd(&bcur16[(b0 + 2) * 16], l2) : 0;
    __syncthreads();
    // stage records bucket-sorted in LDS
    for (int i = t; i < n; i += 256) {
        int c = col[base + i];
        int r = row[base + i];
        int b = c >> BSHIFT;
        int pos = atomicAdd(&lcur[b], 1);
        srec[pos] = (unsigned)r | ((unsigned)(c & 255) << 18);
        sbid[pos] = (unsigned short)b;
    }
    __syncthreads();
    // dense write-out: consecutive slots -> consecutive global addresses per bucket run
    for (int i = t; i < n; i += 256) {
        int b = sbid[i];
        bin[gbase[b] + (i - lscan[b])] = srec[i];
    }
}

// ---- pass 3: within-bucket node sort + deg/dis/off (all free from LDS hist) ----
__global__ void sortpass2(const unsigned* __restrict__ bin, const int* __restrict__ bbase,
                          float* __restrict__ dis, int* __restrict__ off,
                          unsigned* __restrict__ ewf) {
    __shared__ int hist[256];
    __shared__ int sc[256];
    __shared__ int ncur[256];
    int b = blockIdx.x, t = threadIdx.x;
    int s = bbase[b], e = bbase[b + 1];
    hist[t] = 0;
    __syncthreads();
    for (int i = s + t; i < e; i += 256)
        atomicAdd(&hist[bin[i] >> 18], 1);
    __syncthreads();
    int val = hist[t];
    sc[t] = val;
    __syncthreads();
    for (int ofs = 1; ofs < 256; ofs <<= 1) {
        int xv = (t >= ofs) ? sc[t - ofs] : 0;
        __syncthreads();
        sc[t] += xv;
        __syncthreads();
    }
    int ex = sc[t] - val;  // exclusive scan
    ncur[t] = ex;
    int node = (b << BSHIFT) + t;
    if (node < N_NODES) {
        dis[node] = (val > 0) ? (1.0f / sqrtf((float)val)) : 0.0f;
        off[node] = s + ex;
    }
    __syncthreads();
    for (int i = s + t; i < e; i += 256) {
        unsigned rec = bin[i];
        int c = (int)(rec >> 18);
        int pos = s + atomicAdd(&ncur[c], 1);
        ewf[pos] = rec & 0x3FFFFu;
    }
}

// ---- propagation layer: wave64 per dest node, 4 edge-groups x 16 lanes x float4 ----
template <bool FINAL>
__global__ void layer4(const float4* __restrict__ h4, const int* __restrict__ off,
                       const unsigned* __restrict__ ewf, const float* __restrict__ dis,
                       float4* __restrict__ hout4, const float4* __restrict__ hA4,
                       const float4* __restrict__ hB4, float4* __restrict__ out4,
                       float alpha) {
    int wid = (blockIdx.x * blockDim.x + threadIdx.x) >> 6;
    if (wid >= N_NODES) return;
    int lane = threadIdx.x & 63;
    int g = lane >> 4;    // edge group 0..3
    int sub = lane & 15;  // float4 slot within D=64
    int s = off[wid], e = off[wid + 1];
    float4 acc = make_float4(0.f, 0.f, 0.f, 0.f);
    int i = s + g;
    for (; i + 4 < e; i += 8) {  // 2 edges per group in flight
        unsigned r0 = ewf[i];
        unsigned r1 = ewf[i + 4];
        float w0 = dis[r0];
        float w1 = dis[r1];
        float4 v0 = h4[(size_t)r0 * 16 + sub];
        float4 v1 = h4[(size_t)r1 * 16 + sub];
        acc.x += w0 * v0.x; acc.y += w0 * v0.y; acc.z += w0 * v0.z; acc.w += w0 * v0.w;
        acc.x += w1 * v1.x; acc.y += w1 * v1.y; acc.z += w1 * v1.z; acc.w += w1 * v1.w;
    }
    if (i < e) {
        unsigned r = ewf[i];
        float w = dis[r];
        float4 v = h4[(size_t)r * 16 + sub];
        acc.x += w * v.x; acc.y += w * v.y; acc.z += w * v.z; acc.w += w * v.w;
    }
#pragma unroll
    for (int m = 16; m <= 32; m <<= 1) {
        acc.x += __shfl_xor(acc.x, m, 64);
        acc.y += __shfl_xor(acc.y, m, 64);
        acc.z += __shfl_xor(acc.z, m, 64);
        acc.w += __shfl_xor(acc.w, m, 64);
    }
    if (g == 0) {
        float w = dis[wid];
        size_t o = (size_t)wid * 16 + sub;
        if (FINAL) {
            float4 a = hA4[o], bb = hB4[o];
            out4[o] = make_float4(alpha * (a.x + bb.x + w * acc.x),
                                  alpha * (a.y + bb.y + w * acc.y),
                                  alpha * (a.z + bb.z + w * acc.z),
                                  alpha * (a.w + bb.w + w * acc.w));
        } else {
            hout4[o] = make_float4(w * acc.x, w * acc.y, w * acc.z, w * acc.w);
        }
    }
}

extern "C" void kernel_launch(void* const* d_in, const int* in_sizes, int n_in,
                              void* d_out, int out_size, void* d_ws, size_t ws_size,
                              hipStream_t stream) {
    const float* x = (const float*)d_in[0];
    const int* edges = (const int*)d_in[1];
    const int* row = edges;          // edge_index[0]
    const int* col = edges + NEDGE;  // edge_index[1]
    float4* out4 = (float4*)d_out;

    char* ws = (char*)d_ws;
    size_t p = 0;
    auto alloc = [&](size_t bytes) {
        void* r = ws + p;
        p += (bytes + 255) & ~(size_t)255;
        return r;
    };
    int* bcount = (int*)alloc((size_t)NBUCKET * 4);
    int* bbase = (int*)alloc((size_t)(NBUCKET + 1) * 4);
    int* bcur16 = (int*)alloc((size_t)NBPAD * 16 * 4);  // 64B-padded cursors
    float* dis = (float*)alloc((size_t)N_NODES * 4);
    int* off = (int*)alloc((size_t)(N_NODES + 1) * 4);
    unsigned* ewf = (unsigned*)alloc((size_t)NEDGE * 4);
    // bin is dead after sortpass2; hA first written by layer 1 -> alias
    char* region = (char*)alloc((size_t)N_NODES * D * 4);  // 38.4 MB >= bin's 19.2 MB
    unsigned* bin = (unsigned*)region;
    float* hA = (float*)region;
    float* hB = (float*)alloc((size_t)N_NODES * D * 4);

    hipMemsetAsync(bcount, 0, (size_t)NBUCKET * 4, stream);
    hist_bucket<<<512, 256, 0, stream>>>((const int4*)col, bcount);
    scan_buckets<<<1, 256, 0, stream>>>(bcount, bbase, bcur16, off);
    binpass2<<<NBIN_BLOCKS, 256, 0, stream>>>(row, col, bcur16, bin);
    sortpass2<<<NBUCKET, 256, 0, stream>>>(bin, bbase, dis, off, ewf);

    const float alpha = 1.0f / (1.0f + NUM_LAYERS);
    int grid = (N_NODES * 64 + 255) / 256;  // one wave64 per node
    layer4<false><<<grid, 256, 0, stream>>>((const float4*)x, off, ewf, dis,
                                            (float4*)hA, nullptr, nullptr, nullptr, alpha);
    layer4<false><<<grid, 256, 0, stream>>>((const float4*)hA, off, ewf, dis,
                                            (float4*)hB, nullptr, nullptr, nullptr, alpha);
    layer4<true><<<grid, 256, 0, stream>>>((const float4*)hB, off, ewf, dis,
                                           nullptr, (const float4*)hA, (const float4*)hB,
                                           out4, alpha);
}

// Round 5
// 419.179 us; speedup vs baseline: 5.8059x; 1.5161x over previous
//
#include <hip/hip_runtime.h>
#include <hip/hip_fp16.h>
#include <math.h>

#define N_NODES 150000
#define D 64
#define NEDGE 4800000
#define NUM_LAYERS 3

#define BSHIFT 8
#define NBUCKET ((N_NODES + 255) >> 8)  // 586
#define NBPAD 768                        // 3*256, padded scan width
#define BINTILE 8192
#define NBIN_BLOCKS ((NEDGE + BINTILE - 1) / BINTILE)  // 586

// ---- pass 0: per-bucket edge counts (LDS hist, 1 global atomic/bucket/block) ----
__global__ void hist_bucket(const int4* __restrict__ col4, int* __restrict__ bcount) {
    __shared__ int h[NBUCKET];
    for (int i = threadIdx.x; i < NBUCKET; i += blockDim.x) h[i] = 0;
    __syncthreads();
    int i = blockIdx.x * blockDim.x + threadIdx.x;
    int stride = gridDim.x * blockDim.x;
    for (int e = i; e < NEDGE / 4; e += stride) {
        int4 c = col4[e];
        atomicAdd(&h[c.x >> BSHIFT], 1);
        atomicAdd(&h[c.y >> BSHIFT], 1);
        atomicAdd(&h[c.z >> BSHIFT], 1);
        atomicAdd(&h[c.w >> BSHIFT], 1);
    }
    __syncthreads();
    for (int b = threadIdx.x; b < NBUCKET; b += blockDim.x)
        if (h[b]) atomicAdd(&bcount[b], h[b]);
}

// ---- pass 1: scan bucket counts -> bases; init padded cursors ----
__global__ void scan_buckets(const int* __restrict__ bcount, int* __restrict__ bbase,
                             int* __restrict__ bcur16, int* __restrict__ off) {
    __shared__ int tsum[256];
    int t = threadIdx.x;
    int loc[3];
    int s = 0;
#pragma unroll
    for (int k = 0; k < 3; k++) {
        int idx = t * 3 + k;
        int x = (idx < NBUCKET) ? bcount[idx] : 0;
        loc[k] = x;
        s += x;
    }
    tsum[t] = s;
    __syncthreads();
    for (int ofs = 1; ofs < 256; ofs <<= 1) {
        int xv = (t >= ofs) ? tsum[t - ofs] : 0;
        __syncthreads();
        tsum[t] += xv;
        __syncthreads();
    }
    int run = (t > 0) ? tsum[t - 1] : 0;
#pragma unroll
    for (int k = 0; k < 3; k++) {
        int idx = t * 3 + k;
        if (idx < NBUCKET) bbase[idx] = run;
        bcur16[idx * 16] = run;
        run += loc[k];
    }
    if (t == 255) {
        bbase[NBUCKET] = NEDGE;
        off[N_NODES] = NEDGE;
    }
}

// ---- pass 2: bucket-sort edges; col tile in LDS, direct global write (L2 merges) ----
__global__ void __launch_bounds__(256) binpass2(const int* __restrict__ row,
                                                const int* __restrict__ col,
                                                int* __restrict__ bcur16,
                                                unsigned* __restrict__ bin) {
    __shared__ int scol[BINTILE];
    __shared__ int hist[NBPAD];
    __shared__ int lscan[NBPAD];
    __shared__ int lcur[NBPAD];
    __shared__ int gbase[NBPAD];
    __shared__ int tsum[256];
    int t = threadIdx.x;
    int base = blockIdx.x * BINTILE;
    int n = NEDGE - base;
    if (n > BINTILE) n = BINTILE;
    // NEDGE % 4 == 0 and BINTILE % 4 == 0, so n % 4 == 0 in every tile
    const int4* c4 = (const int4*)(col + base);
    int n4 = n >> 2;
    for (int i = t; i < n4; i += 256) ((int4*)scol)[i] = c4[i];
    for (int i = t; i < NBPAD; i += 256) hist[i] = 0;
    __syncthreads();
    for (int i = t; i < n; i += 256)
        atomicAdd(&hist[scol[i] >> BSHIFT], 1);
    __syncthreads();
    int b0 = t * 3;
    int l0 = hist[b0], l1 = hist[b0 + 1], l2 = hist[b0 + 2];
    tsum[t] = l0 + l1 + l2;
    __syncthreads();
    for (int ofs = 1; ofs < 256; ofs <<= 1) {
        int xv = (t >= ofs) ? tsum[t - ofs] : 0;
        __syncthreads();
        tsum[t] += xv;
        __syncthreads();
    }
    int run = (t > 0) ? tsum[t - 1] : 0;
    lscan[b0] = run; lcur[b0] = run;
    lscan[b0 + 1] = run + l0; lcur[b0 + 1] = run + l0;
    lscan[b0 + 2] = run + l0 + l1; lcur[b0 + 2] = run + l0 + l1;
    gbase[b0]     = l0 ? atomicAdd(&bcur16[b0 * 16], l0) : 0;
    gbase[b0 + 1] = l1 ? atomicAdd(&bcur16[(b0 + 1) * 16], l1) : 0;
    gbase[b0 + 2] = l2 ? atomicAdd(&bcur16[(b0 + 2) * 16], l2) : 0;
    __syncthreads();
    for (int i = t; i < n; i += 256) {
        int c = scol[i];
        int r = row[base + i];
        int b = c >> BSHIFT;
        int pos = atomicAdd(&lcur[b], 1) - lscan[b];
        bin[gbase[b] + pos] = (unsigned)r | ((unsigned)(c & 255) << 18);
    }
}

// ---- pass 3: within-bucket node sort + deg/dis/off (free from LDS hist) ----
__global__ void sortpass2(const unsigned* __restrict__ bin, const int* __restrict__ bbase,
                          float* __restrict__ dis, int* __restrict__ off,
                          unsigned* __restrict__ ewf) {
    __shared__ int hist[256];
    __shared__ int sc[256];
    __shared__ int ncur[256];
    int b = blockIdx.x, t = threadIdx.x;
    int s = bbase[b], e = bbase[b + 1];
    hist[t] = 0;
    __syncthreads();
    for (int i = s + t; i < e; i += 256)
        atomicAdd(&hist[bin[i] >> 18], 1);
    __syncthreads();
    int val = hist[t];
    sc[t] = val;
    __syncthreads();
    for (int ofs = 1; ofs < 256; ofs <<= 1) {
        int xv = (t >= ofs) ? sc[t - ofs] : 0;
        __syncthreads();
        sc[t] += xv;
        __syncthreads();
    }
    int ex = sc[t] - val;
    ncur[t] = ex;
    int node = (b << BSHIFT) + t;
    if (node < N_NODES) {
        dis[node] = (val > 0) ? (1.0f / sqrtf((float)val)) : 0.0f;
        off[node] = s + ex;
    }
    __syncthreads();
    for (int i = s + t; i < e; i += 256) {
        unsigned rec = bin[i];
        int c = (int)(rec >> 18);
        int pos = s + atomicAdd(&ncur[c], 1);
        ewf[pos] = rec & 0x3FFFFu;
    }
}

// ---- convert x (fp32) -> xh (fp16 rows) ----
__global__ void cvt_x(const float4* __restrict__ x4, uint2* __restrict__ xh) {
    int i = blockIdx.x * blockDim.x + threadIdx.x;
    if (i >= N_NODES * 16) return;
    float4 v = x4[i];
    __half2 a = __floats2half2_rn(v.x, v.y);
    __half2 b = __floats2half2_rn(v.z, v.w);
    uint2 r;
    r.x = *reinterpret_cast<unsigned*>(&a);
    r.y = *reinterpret_cast<unsigned*>(&b);
    xh[i] = r;
}

// ---- propagation layer: wave64 per node, 8 edge-groups x 8 lanes, fp16 rows ----
template <bool FINAL>
__global__ void layer8(const uint4* __restrict__ h8, const int* __restrict__ off,
                       const unsigned* __restrict__ ewf, const float* __restrict__ dis,
                       uint4* __restrict__ hout, const uint4* __restrict__ hA,
                       const uint4* __restrict__ hB, float4* __restrict__ out4,
                       float alpha) {
    int wid = (blockIdx.x * blockDim.x + threadIdx.x) >> 6;
    if (wid >= N_NODES) return;
    int lane = threadIdx.x & 63;
    int g = lane >> 3;    // edge group 0..7
    int sub = lane & 7;   // 16B slot within 128B fp16 row
    int s = off[wid], e = off[wid + 1];
    float acc[8];
#pragma unroll
    for (int k = 0; k < 8; k++) acc[k] = 0.f;

    auto ACC = [&](uint4 v, float w) {
        const __half2* p = reinterpret_cast<const __half2*>(&v);
#pragma unroll
        for (int k = 0; k < 4; k++) {
            float2 f = __half22float2(p[k]);
            acc[2 * k]     = fmaf(w, f.x, acc[2 * k]);
            acc[2 * k + 1] = fmaf(w, f.y, acc[2 * k + 1]);
        }
    };

    int i = s + g;
    for (; i + 24 < e; i += 32) {  // 4 edges per group in flight
        unsigned r0 = ewf[i], r1 = ewf[i + 8], r2 = ewf[i + 16], r3 = ewf[i + 24];
        float w0 = dis[r0], w1 = dis[r1], w2 = dis[r2], w3 = dis[r3];
        uint4 v0 = h8[(size_t)r0 * 8 + sub];
        uint4 v1 = h8[(size_t)r1 * 8 + sub];
        uint4 v2 = h8[(size_t)r2 * 8 + sub];
        uint4 v3 = h8[(size_t)r3 * 8 + sub];
        ACC(v0, w0); ACC(v1, w1); ACC(v2, w2); ACC(v3, w3);
    }
    for (; i < e; i += 8) {
        unsigned r = ewf[i];
        float w = dis[r];
        uint4 v = h8[(size_t)r * 8 + sub];
        ACC(v, w);
    }
    // reduce the 8 edge groups (lanes sharing sub)
#pragma unroll
    for (int m = 8; m <= 32; m <<= 1)
#pragma unroll
        for (int k = 0; k < 8; k++) acc[k] += __shfl_xor(acc[k], m, 64);

    if (g != 0) return;
    float w = dis[wid];
    if (FINAL) {
        uint4 a = hA[(size_t)wid * 8 + sub];
        uint4 b = hB[(size_t)wid * 8 + sub];
        const __half2* pa = reinterpret_cast<const __half2*>(&a);
        const __half2* pb = reinterpret_cast<const __half2*>(&b);
        float r[8];
#pragma unroll
        for (int k = 0; k < 4; k++) {
            float2 fa = __half22float2(pa[k]);
            float2 fb = __half22float2(pb[k]);
            r[2 * k]     = alpha * (fa.x + fb.x + w * acc[2 * k]);
            r[2 * k + 1] = alpha * (fa.y + fb.y + w * acc[2 * k + 1]);
        }
        out4[(size_t)wid * 16 + sub * 2]     = make_float4(r[0], r[1], r[2], r[3]);
        out4[(size_t)wid * 16 + sub * 2 + 1] = make_float4(r[4], r[5], r[6], r[7]);
    } else {
        __half2 q[4];
#pragma unroll
        for (int k = 0; k < 4; k++)
            q[k] = __floats2half2_rn(w * acc[2 * k], w * acc[2 * k + 1]);
        uint4 st;
        st.x = *reinterpret_cast<unsigned*>(&q[0]);
        st.y = *reinterpret_cast<unsigned*>(&q[1]);
        st.z = *reinterpret_cast<unsigned*>(&q[2]);
        st.w = *reinterpret_cast<unsigned*>(&q[3]);
        hout[(size_t)wid * 8 + sub] = st;
    }
}

extern "C" void kernel_launch(void* const* d_in, const int* in_sizes, int n_in,
                              void* d_out, int out_size, void* d_ws, size_t ws_size,
                              hipStream_t stream) {
    const float* x = (const float*)d_in[0];
    const int* edges = (const int*)d_in[1];
    const int* row = edges;          // edge_index[0]
    const int* col = edges + NEDGE;  // edge_index[1]
    float4* out4 = (float4*)d_out;

    char* ws = (char*)d_ws;
    size_t p = 0;
    auto alloc = [&](size_t bytes) {
        void* r = ws + p;
        p += (bytes + 255) & ~(size_t)255;
        return r;
    };
    int* bcount = (int*)alloc((size_t)NBUCKET * 4);
    int* bbase = (int*)alloc((size_t)(NBUCKET + 1) * 4);
    int* bcur16 = (int*)alloc((size_t)NBPAD * 16 * 4);
    float* dis = (float*)alloc((size_t)N_NODES * 4);
    int* off = (int*)alloc((size_t)(N_NODES + 1) * 4);
    unsigned* ewf = (unsigned*)alloc((size_t)NEDGE * 4);
    uint2* xh = (uint2*)alloc((size_t)N_NODES * D * 2);  // fp16 x
    // bin (19.2MB) dead after sortpass2; hA (fp16, 19.2MB) first written after -> alias
    char* region = (char*)alloc((size_t)N_NODES * D * 2);
    unsigned* bin = (unsigned*)region;
    uint4* hA = (uint4*)region;
    uint4* hB = (uint4*)alloc((size_t)N_NODES * D * 2);

    hipMemsetAsync(bcount, 0, (size_t)NBUCKET * 4, stream);
    cvt_x<<<(N_NODES * 16 + 255) / 256, 256, 0, stream>>>((const float4*)x, xh);
    hist_bucket<<<512, 256, 0, stream>>>((const int4*)col, bcount);
    scan_buckets<<<1, 256, 0, stream>>>(bcount, bbase, bcur16, off);
    binpass2<<<NBIN_BLOCKS, 256, 0, stream>>>(row, col, bcur16, bin);
    sortpass2<<<NBUCKET, 256, 0, stream>>>(bin, bbase, dis, off, ewf);

    const float alpha = 1.0f / (1.0f + NUM_LAYERS);
    int grid = (N_NODES * 64 + 255) / 256;  // one wave64 per node
    layer8<false><<<grid, 256, 0, stream>>>((const uint4*)xh, off, ewf, dis,
                                            hA, nullptr, nullptr, nullptr, alpha);
    layer8<false><<<grid, 256, 0, stream>>>((const uint4*)hA, off, ewf, dis,
                                            hB, nullptr, nullptr, nullptr, alpha);
    layer8<true><<<grid, 256, 0, stream>>>((const uint4*)hB, off, ewf, dis,
                                           nullptr, (const uint4*)hA, (const uint4*)hB,
                                           out4, alpha);
}

// Round 6
// 406.738 us; speedup vs baseline: 5.9835x; 1.0306x over previous
//
#include <hip/hip_runtime.h>
#include <hip/hip_fp16.h>
#include <math.h>

#define N_NODES 150000
#define D 64
#define NEDGE 4800000
#define NUM_LAYERS 3

#define BSHIFT 8
#define NBUCKET ((N_NODES + 255) >> 8)  // 586
#define NBPAD 768                        // 3*256, padded scan width
#define BINTILE 8192
#define NBIN_BLOCKS ((NEDGE + BINTILE - 1) / BINTILE)  // 586

// ---- pass 0: per-bucket edge counts (LDS hist, 1 global atomic/bucket/block) ----
__global__ void hist_bucket(const int4* __restrict__ col4, int* __restrict__ bcount) {
    __shared__ int h[NBUCKET];
    for (int i = threadIdx.x; i < NBUCKET; i += blockDim.x) h[i] = 0;
    __syncthreads();
    int i = blockIdx.x * blockDim.x + threadIdx.x;
    int stride = gridDim.x * blockDim.x;
    for (int e = i; e < NEDGE / 4; e += stride) {
        int4 c = col4[e];
        atomicAdd(&h[c.x >> BSHIFT], 1);
        atomicAdd(&h[c.y >> BSHIFT], 1);
        atomicAdd(&h[c.z >> BSHIFT], 1);
        atomicAdd(&h[c.w >> BSHIFT], 1);
    }
    __syncthreads();
    for (int b = threadIdx.x; b < NBUCKET; b += blockDim.x)
        if (h[b]) atomicAdd(&bcount[b], h[b]);
}

// ---- pass 1: scan bucket counts -> bases; init padded cursors ----
__global__ void scan_buckets(const int* __restrict__ bcount, int* __restrict__ bbase,
                             int* __restrict__ bcur16, int* __restrict__ off) {
    __shared__ int tsum[256];
    int t = threadIdx.x;
    int loc[3];
    int s = 0;
#pragma unroll
    for (int k = 0; k < 3; k++) {
        int idx = t * 3 + k;
        int x = (idx < NBUCKET) ? bcount[idx] : 0;
        loc[k] = x;
        s += x;
    }
    tsum[t] = s;
    __syncthreads();
    for (int ofs = 1; ofs < 256; ofs <<= 1) {
        int xv = (t >= ofs) ? tsum[t - ofs] : 0;
        __syncthreads();
        tsum[t] += xv;
        __syncthreads();
    }
    int run = (t > 0) ? tsum[t - 1] : 0;
#pragma unroll
    for (int k = 0; k < 3; k++) {
        int idx = t * 3 + k;
        if (idx < NBUCKET) bbase[idx] = run;
        bcur16[idx * 16] = run;
        run += loc[k];
    }
    if (t == 255) {
        bbase[NBUCKET] = NEDGE;
        off[N_NODES] = NEDGE;
    }
}

// ---- pass 2: bucket-sort edges; LDS-staged records, per-thread ordered run write-out ----
__global__ void __launch_bounds__(256) binpass2(const int* __restrict__ row,
                                                const int* __restrict__ col,
                                                int* __restrict__ bcur16,
                                                unsigned* __restrict__ bin) {
    __shared__ unsigned srec[BINTILE];  // 32 KB, bucket-sorted records
    __shared__ int hist[NBPAD];
    __shared__ int lscan[NBPAD];
    __shared__ int lcur[NBPAD];
    __shared__ int gbase[NBPAD];
    __shared__ int tsum[256];
    int t = threadIdx.x;
    int base = blockIdx.x * BINTILE;
    int n = NEDGE - base;
    if (n > BINTILE) n = BINTILE;
    for (int i = t; i < NBPAD; i += 256) hist[i] = 0;
    __syncthreads();
    for (int i = t; i < n; i += 256)
        atomicAdd(&hist[col[base + i] >> BSHIFT], 1);
    __syncthreads();
    int b0 = t * 3;
    int l0 = hist[b0], l1 = hist[b0 + 1], l2 = hist[b0 + 2];
    tsum[t] = l0 + l1 + l2;
    __syncthreads();
    for (int ofs = 1; ofs < 256; ofs <<= 1) {
        int xv = (t >= ofs) ? tsum[t - ofs] : 0;
        __syncthreads();
        tsum[t] += xv;
        __syncthreads();
    }
    int run = (t > 0) ? tsum[t - 1] : 0;
    lscan[b0] = run; lcur[b0] = run;
    lscan[b0 + 1] = run + l0; lcur[b0 + 1] = run + l0;
    lscan[b0 + 2] = run + l0 + l1; lcur[b0 + 2] = run + l0 + l1;
    gbase[b0]     = l0 ? atomicAdd(&bcur16[b0 * 16], l0) : 0;
    gbase[b0 + 1] = l1 ? atomicAdd(&bcur16[(b0 + 1) * 16], l1) : 0;
    gbase[b0 + 2] = l2 ? atomicAdd(&bcur16[(b0 + 2) * 16], l2) : 0;
    __syncthreads();
    // stage records bucket-sorted in LDS (second global read of col)
    for (int i = t; i < n; i += 256) {
        int c = col[base + i];
        int r = row[base + i];
        int b = c >> BSHIFT;
        int pos = atomicAdd(&lcur[b], 1);
        srec[pos] = (unsigned)r | ((unsigned)(c & 255) << 18);
    }
    __syncthreads();
    // write-out: thread t copies its 3 buckets' runs contiguously
#pragma unroll
    for (int k = 0; k < 3; k++) {
        int b = b0 + k;
        int s = lscan[b], e2 = lcur[b], gb = gbase[b];
        for (int j = s; j < e2; j++) bin[gb + (j - s)] = srec[j];
    }
}

// ---- pass 3: within-bucket node sort + deg/dis/off (free from LDS hist) ----
__global__ void sortpass2(const unsigned* __restrict__ bin, const int* __restrict__ bbase,
                          float* __restrict__ dis, int* __restrict__ off,
                          unsigned* __restrict__ ewf) {
    __shared__ int hist[256];
    __shared__ int sc[256];
    __shared__ int ncur[256];
    int b = blockIdx.x, t = threadIdx.x;
    int s = bbase[b], e = bbase[b + 1];
    hist[t] = 0;
    __syncthreads();
    for (int i = s + t; i < e; i += 256)
        atomicAdd(&hist[bin[i] >> 18], 1);
    __syncthreads();
    int val = hist[t];
    sc[t] = val;
    __syncthreads();
    for (int ofs = 1; ofs < 256; ofs <<= 1) {
        int xv = (t >= ofs) ? sc[t - ofs] : 0;
        __syncthreads();
        sc[t] += xv;
        __syncthreads();
    }
    int ex = sc[t] - val;
    ncur[t] = ex;
    int node = (b << BSHIFT) + t;
    if (node < N_NODES) {
        dis[node] = (val > 0) ? (1.0f / sqrtf((float)val)) : 0.0f;
        off[node] = s + ex;
    }
    __syncthreads();
    for (int i = s + t; i < e; i += 256) {
        unsigned rec = bin[i];
        int c = (int)(rec >> 18);
        int pos = s + atomicAdd(&ncur[c], 1);
        ewf[pos] = rec & 0x3FFFFu;
    }
}

// ---- convert x (fp32) -> xh (fp16 rows) ----
__global__ void cvt_x(const float4* __restrict__ x4, uint2* __restrict__ xh) {
    int i = blockIdx.x * blockDim.x + threadIdx.x;
    if (i >= N_NODES * 16) return;
    float4 v = x4[i];
    __half2 a = __floats2half2_rn(v.x, v.y);
    __half2 b = __floats2half2_rn(v.z, v.w);
    uint2 r;
    r.x = *reinterpret_cast<unsigned*>(&a);
    r.y = *reinterpret_cast<unsigned*>(&b);
    xh[i] = r;
}

// ---- propagation layer: wave64 per node, 8 edge-groups x 8 lanes, fp16 rows ----
template <bool FINAL>
__global__ void layer8(const uint4* __restrict__ h8, const int* __restrict__ off,
                       const unsigned* __restrict__ ewf, const float* __restrict__ dis,
                       uint4* __restrict__ hout, const uint4* __restrict__ hA,
                       const uint4* __restrict__ hB, float4* __restrict__ out4,
                       float alpha) {
    int wid = (blockIdx.x * blockDim.x + threadIdx.x) >> 6;
    if (wid >= N_NODES) return;
    int lane = threadIdx.x & 63;
    int g = lane >> 3;    // edge group 0..7
    int sub = lane & 7;   // 16B slot within 128B fp16 row
    int s = off[wid], e = off[wid + 1];
    float acc[8];
#pragma unroll
    for (int k = 0; k < 8; k++) acc[k] = 0.f;

    auto ACC = [&](uint4 v, float w) {
        const __half2* p = reinterpret_cast<const __half2*>(&v);
#pragma unroll
        for (int k = 0; k < 4; k++) {
            float2 f = __half22float2(p[k]);
            acc[2 * k]     = fmaf(w, f.x, acc[2 * k]);
            acc[2 * k + 1] = fmaf(w, f.y, acc[2 * k + 1]);
        }
    };

    int i = s + g;
    for (; i + 24 < e; i += 32) {  // 4 edges per group in flight
        unsigned r0 = ewf[i], r1 = ewf[i + 8], r2 = ewf[i + 16], r3 = ewf[i + 24];
        float w0 = dis[r0], w1 = dis[r1], w2 = dis[r2], w3 = dis[r3];
        uint4 v0 = h8[(size_t)r0 * 8 + sub];
        uint4 v1 = h8[(size_t)r1 * 8 + sub];
        uint4 v2 = h8[(size_t)r2 * 8 + sub];
        uint4 v3 = h8[(size_t)r3 * 8 + sub];
        ACC(v0, w0); ACC(v1, w1); ACC(v2, w2); ACC(v3, w3);
    }
    for (; i < e; i += 8) {
        unsigned r = ewf[i];
        float w = dis[r];
        uint4 v = h8[(size_t)r * 8 + sub];
        ACC(v, w);
    }
#pragma unroll
    for (int m = 8; m <= 32; m <<= 1)
#pragma unroll
        for (int k = 0; k < 8; k++) acc[k] += __shfl_xor(acc[k], m, 64);

    if (g != 0) return;
    float w = dis[wid];
    if (FINAL) {
        uint4 a = hA[(size_t)wid * 8 + sub];
        uint4 b = hB[(size_t)wid * 8 + sub];
        const __half2* pa = reinterpret_cast<const __half2*>(&a);
        const __half2* pb = reinterpret_cast<const __half2*>(&b);
        float r[8];
#pragma unroll
        for (int k = 0; k < 4; k++) {
            float2 fa = __half22float2(pa[k]);
            float2 fb = __half22float2(pb[k]);
            r[2 * k]     = alpha * (fa.x + fb.x + w * acc[2 * k]);
            r[2 * k + 1] = alpha * (fa.y + fb.y + w * acc[2 * k + 1]);
        }
        out4[(size_t)wid * 16 + sub * 2]     = make_float4(r[0], r[1], r[2], r[3]);
        out4[(size_t)wid * 16 + sub * 2 + 1] = make_float4(r[4], r[5], r[6], r[7]);
    } else {
        __half2 q[4];
#pragma unroll
        for (int k = 0; k < 4; k++)
            q[k] = __floats2half2_rn(w * acc[2 * k], w * acc[2 * k + 1]);
        uint4 st;
        st.x = *reinterpret_cast<unsigned*>(&q[0]);
        st.y = *reinterpret_cast<unsigned*>(&q[1]);
        st.z = *reinterpret_cast<unsigned*>(&q[2]);
        st.w = *reinterpret_cast<unsigned*>(&q[3]);
        hout[(size_t)wid * 8 + sub] = st;
    }
}

extern "C" void kernel_launch(void* const* d_in, const int* in_sizes, int n_in,
                              void* d_out, int out_size, void* d_ws, size_t ws_size,
                              hipStream_t stream) {
    const float* x = (const float*)d_in[0];
    const int* edges = (const int*)d_in[1];
    const int* row = edges;          // edge_index[0]
    const int* col = edges + NEDGE;  // edge_index[1]
    float4* out4 = (float4*)d_out;

    char* ws = (char*)d_ws;
    size_t p = 0;
    auto alloc = [&](size_t bytes) {
        void* r = ws + p;
        p += (bytes + 255) & ~(size_t)255;
        return r;
    };
    int* bcount = (int*)alloc((size_t)NBUCKET * 4);
    int* bbase = (int*)alloc((size_t)(NBUCKET + 1) * 4);
    int* bcur16 = (int*)alloc((size_t)NBPAD * 16 * 4);
    float* dis = (float*)alloc((size_t)N_NODES * 4);
    int* off = (int*)alloc((size_t)(N_NODES + 1) * 4);
    unsigned* ewf = (unsigned*)alloc((size_t)NEDGE * 4);
    uint2* xh = (uint2*)alloc((size_t)N_NODES * D * 2);  // fp16 x
    // bin (19.2MB) dead after sortpass2; hA (fp16, 19.2MB) first written after -> alias
    char* region = (char*)alloc((size_t)N_NODES * D * 2);
    unsigned* bin = (unsigned*)region;
    uint4* hA = (uint4*)region;
    uint4* hB = (uint4*)alloc((size_t)N_NODES * D * 2);

    hipMemsetAsync(bcount, 0, (size_t)NBUCKET * 4, stream);
    cvt_x<<<(N_NODES * 16 + 255) / 256, 256, 0, stream>>>((const float4*)x, xh);
    hist_bucket<<<512, 256, 0, stream>>>((const int4*)col, bcount);
    scan_buckets<<<1, 256, 0, stream>>>(bcount, bbase, bcur16, off);
    binpass2<<<NBIN_BLOCKS, 256, 0, stream>>>(row, col, bcur16, bin);
    sortpass2<<<NBUCKET, 256, 0, stream>>>(bin, bbase, dis, off, ewf);

    const float alpha = 1.0f / (1.0f + NUM_LAYERS);
    int grid = (N_NODES * 64 + 255) / 256;  // one wave64 per node
    layer8<false><<<grid, 256, 0, stream>>>((const uint4*)xh, off, ewf, dis,
                                            hA, nullptr, nullptr, nullptr, alpha);
    layer8<false><<<grid, 256, 0, stream>>>((const uint4*)hA, off, ewf, dis,
                                            hB, nullptr, nullptr, nullptr, alpha);
    layer8<true><<<grid, 256, 0, stream>>>((const uint4*)hB, off, ewf, dis,
                                           nullptr, (const uint4*)hA, (const uint4*)hB,
                                           out4, alpha);
}